// Round 10
// baseline (29.243 us; speedup 1.0000x reference)
//
#include <hip/hip_runtime.h>

// SVR: out[i] = sum_j exp(-|f_i-f_j|^2/50)*alpha[j] + bias.  N=4096, D=64.
// Round 10: INSTRUMENTED A/B. R9 kernels kept verbatim (prep, ref-main->scratch,
// reduce) + new 4-i-tile main (svr_mfma4) as the real producer.
//   wall_R10 - wall_R9 = svr_mfma4 time (stream capture serializes dispatches)
// svr_mfma4: wave holds 4 i-tiles of B-frags (64 rows); per j-tile iteration
// 2 A-loads feed 8 MFMAs (A-traffic/output /4, ILP x4). Grid (16,32).
//
// Frag map (16x16x32 bf16): lane l of tile t, half h: row=16*t+(l&15),
// k=32*h+(l>>4)*8..+7 -> chunk (t*2+h)*64+l.  A/B share lane->k map.
// C/D: col=lane&15 (i), row=(lane>>4)*4+reg (j)  [verified m89; R4-R9 passed]
// exp2 domain: exp(-(si+sj-2dot)/50) = exp2(dot*K1 - si2 - sj2).

#define NN 4096
#define DD 64
#define NPY 32                 // j-chunks for mfma4 (8 tiles each)
#define NPO 16                 // j-chunks for ref main (16 tiles each)
#define NT (NN / 16)           // 256 row-tiles

typedef __attribute__((ext_vector_type(8))) short bf16x8;
typedef __attribute__((ext_vector_type(8))) unsigned short u16x8;
typedef __attribute__((ext_vector_type(4))) float f32x4;

#define K1 0.057707802f        // 2*log2(e)/50
#define C2 0.028853901f        // log2(e)/50

static __device__ __forceinline__ unsigned short f2bf(float f) {
    unsigned int x = __float_as_uint(f);
    x += 0x7fffu + ((x >> 16) & 1u);          // RNE
    return (unsigned short)(x >> 16);
}

// ---------- prep: retile+convert; row norms via LDS reduce (R9 verbatim) ----------
__global__ __launch_bounds__(256) void svr_prep(const float* __restrict__ F,
                                                u16x8* __restrict__ Ft,
                                                float* __restrict__ sq2) {
    __shared__ float part[256];
    const int tid = threadIdx.x;
    const int g = blockIdx.x * 256 + tid;
    const int l = g & 63;
    const int h = (g >> 6) & 1;
    const int t = g >> 7;
    const int row = t * 16 + (l & 15);
    const int k0  = h * 32 + (l >> 4) * 8;

    const float4* src = reinterpret_cast<const float4*>(F + (size_t)row * DD + k0);
    const float4 v0 = src[0];
    const float4 v1 = src[1];
    u16x8 u;
    u[0] = f2bf(v0.x); u[1] = f2bf(v0.y); u[2] = f2bf(v0.z); u[3] = f2bf(v0.w);
    u[4] = f2bf(v1.x); u[5] = f2bf(v1.y); u[6] = f2bf(v1.z); u[7] = f2bf(v1.w);
    Ft[g] = u;

    float p = v0.x * v0.x;
    p = fmaf(v0.y, v0.y, p); p = fmaf(v0.z, v0.z, p); p = fmaf(v0.w, v0.w, p);
    p = fmaf(v1.x, v1.x, p); p = fmaf(v1.y, v1.y, p); p = fmaf(v1.z, v1.z, p);
    p = fmaf(v1.w, v1.w, p);
    part[tid] = p;
    __syncthreads();
    if ((tid & 112) == 0) {
        float s = part[tid]      + part[tid + 16] + part[tid + 32] + part[tid + 48]
                + part[tid + 64] + part[tid + 80] + part[tid + 96] + part[tid + 112];
        sq2[row] = s * C2;
    }
}

// ---------- NEW: 4-i-tile main. wave = 64 i-rows x 128 j-rows ----------
__global__ __launch_bounds__(256) void svr_mfma4(const bf16x8* __restrict__ Ft,
                                                 const float* __restrict__ alpha,
                                                 const float* __restrict__ sq2,
                                                 float* __restrict__ ws) {
    const int lane = threadIdx.x & 63;
    const int wave = threadIdx.x >> 6;
    const int ig   = blockIdx.x * 4 + wave;          // i-group 0..63 (64 rows)
    const int it0  = ig * 4;                         // first of 4 i-tiles
    const int iBase = it0 * 16;
    const int p    = blockIdx.y;                     // 0..31
    const int jt0  = p * (NT / NPY);                 // 8 j-tiles
    const int kg   = lane >> 4;
    const int c    = lane & 15;

    // B-frags for 4 i-tiles (resident; 32 VGPR) + their norms
    const bf16x8 b00 = Ft[(it0 + 0) * 128 + lane], b01 = Ft[(it0 + 0) * 128 + 64 + lane];
    const bf16x8 b10 = Ft[(it0 + 1) * 128 + lane], b11 = Ft[(it0 + 1) * 128 + 64 + lane];
    const bf16x8 b20 = Ft[(it0 + 2) * 128 + lane], b21 = Ft[(it0 + 2) * 128 + 64 + lane];
    const bf16x8 b30 = Ft[(it0 + 3) * 128 + lane], b31 = Ft[(it0 + 3) * 128 + 64 + lane];
    const float q0 = sq2[iBase + c],      q1 = sq2[iBase + 16 + c];
    const float q2 = sq2[iBase + 32 + c], q3 = sq2[iBase + 48 + c];

    const float4* sqv = reinterpret_cast<const float4*>(sq2);
    const float4* alv = reinterpret_cast<const float4*>(alpha);

    f32x4 acc0 = {0.f,0.f,0.f,0.f}, acc1 = {0.f,0.f,0.f,0.f};
    f32x4 acc2 = {0.f,0.f,0.f,0.f}, acc3 = {0.f,0.f,0.f,0.f};

    bf16x8 a0 = Ft[jt0 * 128 + lane];
    bf16x8 a1 = Ft[jt0 * 128 + 64 + lane];
    float4 sj = sqv[jt0 * 4 + kg];
    float4 aj = alv[jt0 * 4 + kg];

#pragma unroll
    for (int k = 0; k < NT / NPY; ++k) {
        bf16x8 n0, n1; float4 nsj, naj;
        if (k + 1 < NT / NPY) {
            const int jn = jt0 + k + 1;
            n0 = Ft[jn * 128 + lane];
            n1 = Ft[jn * 128 + 64 + lane];
            nsj = sqv[jn * 4 + kg];
            naj = alv[jn * 4 + kg];
        }
#define TILE(acc, bA, bB, qi)                                              \
        {                                                                  \
            f32x4 d0 = {0.f,0.f,0.f,0.f}, d1 = {0.f,0.f,0.f,0.f};          \
            d0 = __builtin_amdgcn_mfma_f32_16x16x32_bf16(a0, bA, d0, 0,0,0);\
            d1 = __builtin_amdgcn_mfma_f32_16x16x32_bf16(a1, bB, d1, 0,0,0);\
            acc.x = fmaf(exp2f(fmaf(d0[0]+d1[0], K1, -(qi + sj.x))), aj.x, acc.x); \
            acc.y = fmaf(exp2f(fmaf(d0[1]+d1[1], K1, -(qi + sj.y))), aj.y, acc.y); \
            acc.z = fmaf(exp2f(fmaf(d0[2]+d1[2], K1, -(qi + sj.z))), aj.z, acc.z); \
            acc.w = fmaf(exp2f(fmaf(d0[3]+d1[3], K1, -(qi + sj.w))), aj.w, acc.w); \
        }
        TILE(acc0, b00, b01, q0)
        TILE(acc1, b10, b11, q1)
        TILE(acc2, b20, b21, q2)
        TILE(acc3, b30, b31, q3)
#undef TILE
        a0 = n0; a1 = n1; sj = nsj; aj = naj;
    }

    float s0 = (acc0.x + acc0.y) + (acc0.z + acc0.w);
    float s1 = (acc1.x + acc1.y) + (acc1.z + acc1.w);
    float s2 = (acc2.x + acc2.y) + (acc2.z + acc2.w);
    float s3 = (acc3.x + acc3.y) + (acc3.z + acc3.w);
    s0 += __shfl_xor(s0, 16); s0 += __shfl_xor(s0, 32);
    s1 += __shfl_xor(s1, 16); s1 += __shfl_xor(s1, 32);
    s2 += __shfl_xor(s2, 16); s2 += __shfl_xor(s2, 32);
    s3 += __shfl_xor(s3, 16); s3 += __shfl_xor(s3, 32);
    if (lane < 16) {
        float* w = ws + (size_t)p * NN + iBase + lane;
        w[0] = s0; w[16] = s1; w[32] = s2; w[48] = s3;
    }
}

// ---------- REF main (R9 verbatim) -> scratch; timing control ----------
__global__ __launch_bounds__(256) void svr_mfma_ref(const bf16x8* __restrict__ Ft,
                                                    const float* __restrict__ alpha,
                                                    const float* __restrict__ sq2,
                                                    float* __restrict__ ws) {
    const int lane = threadIdx.x & 63;
    const int wave = threadIdx.x >> 6;
    const int it   = blockIdx.x * 4 + wave;
    const int iBase = it * 16;
    const int p    = blockIdx.y;
    const int jt0  = p * (NT / NPO);
    const int kg   = lane >> 4;
    const int c    = lane & 15;

    const bf16x8 b0 = Ft[it * 128 + lane];
    const bf16x8 b1 = Ft[it * 128 + 64 + lane];
    const float si2 = sq2[iBase + c];

    const float4* sqv = reinterpret_cast<const float4*>(sq2);
    const float4* alv = reinterpret_cast<const float4*>(alpha);

    f32x4 acc = {0.f, 0.f, 0.f, 0.f};

    bf16x8 a0 = Ft[jt0 * 128 + lane];
    bf16x8 a1 = Ft[jt0 * 128 + 64 + lane];
    float4 sj = sqv[jt0 * 4 + kg];
    float4 aj = alv[jt0 * 4 + kg];

#pragma unroll
    for (int k = 0; k < NT / NPO; ++k) {
        bf16x8 n0, n1; float4 nsj, naj;
        if (k + 1 < NT / NPO) {
            const int jn = jt0 + k + 1;
            n0 = Ft[jn * 128 + lane];
            n1 = Ft[jn * 128 + 64 + lane];
            nsj = sqv[jn * 4 + kg];
            naj = alv[jn * 4 + kg];
        }
        f32x4 d0 = {0.f, 0.f, 0.f, 0.f};
        f32x4 d1 = {0.f, 0.f, 0.f, 0.f};
        d0 = __builtin_amdgcn_mfma_f32_16x16x32_bf16(a0, b0, d0, 0, 0, 0);
        d1 = __builtin_amdgcn_mfma_f32_16x16x32_bf16(a1, b1, d1, 0, 0, 0);
        acc.x = fmaf(exp2f(fmaf(d0[0] + d1[0], K1, -(si2 + sj.x))), aj.x, acc.x);
        acc.y = fmaf(exp2f(fmaf(d0[1] + d1[1], K1, -(si2 + sj.y))), aj.y, acc.y);
        acc.z = fmaf(exp2f(fmaf(d0[2] + d1[2], K1, -(si2 + sj.z))), aj.z, acc.z);
        acc.w = fmaf(exp2f(fmaf(d0[3] + d1[3], K1, -(si2 + sj.w))), aj.w, acc.w);
        a0 = n0; a1 = n1; sj = nsj; aj = naj;
    }

    float s = (acc.x + acc.y) + (acc.z + acc.w);
    s += __shfl_xor(s, 16);
    s += __shfl_xor(s, 32);
    if (lane < 16) ws[p * NN + iBase + lane] = s;
}

// ---------- reduce: out[i] = bias + sum_{p<32} part[p][i] ----------
__global__ __launch_bounds__(256) void svr_reduce(const float* __restrict__ ws,
                                                  const float* __restrict__ bias,
                                                  float* __restrict__ out) {
    const int i = blockIdx.x * 256 + threadIdx.x;
    float s = bias[0];
#pragma unroll
    for (int p = 0; p < NPY; ++p) s += ws[p * NN + i];
    out[i] = s;
}

// ---------------- launch ----------------
extern "C" void kernel_launch(void* const* d_in, const int* in_sizes, int n_in,
                              void* d_out, int out_size, void* d_ws, size_t ws_size,
                              hipStream_t stream) {
    const float* F     = (const float*)d_in[0];
    const float* alpha = (const float*)d_in[1];
    const float* bias  = (const float*)d_in[2];
    float* out = (float*)d_out;

    u16x8* Ft    = (u16x8*)d_ws;                                   // 512 KB
    float* sq2   = (float*)((char*)d_ws + (size_t)NN * DD * 2);    // 16 KB
    float* part  = sq2 + NN;                                       // 512 KB (32 partials)
    float* part2 = part + (size_t)NPY * NN;                        // 256 KB scratch (ref)

    svr_prep<<<dim3(NN * DD / 8 / 256), dim3(256), 0, stream>>>(F, Ft, sq2);
    svr_mfma4<<<dim3(16, NPY), dim3(256), 0, stream>>>((const bf16x8*)Ft, alpha, sq2, part);
    svr_mfma_ref<<<dim3(NT / 4, NPO), dim3(256), 0, stream>>>((const bf16x8*)Ft, alpha, sq2, part2);
    svr_reduce<<<dim3(NN / 256), dim3(256), 0, stream>>>(part, bias, out);
}

// Round 11
// 17.805 us; speedup vs baseline: 1.6424x; 1.6424x over previous
//
#include <hip/hip_runtime.h>

// SVR: out[i] = sum_j exp(-|f_i-f_j|^2/50)*alpha[j] + bias.  N=4096, D=64.
// Round 11: keep R10's proven 4-i-tile main (6.2us vs 13us by A/B), slim the
// epilogue algebraically, 2 dispatches total:
//   exp(-(si+sj-2dot)/50) = exp2(K1*dot) * exp2(-si2) * exp2(-sj2)
//   - Ft stores bf16(f * sqrt(K1))  -> MFMA emits K1*dot directly (no mul)
//   - ajp[j] = alpha[j]*exp2(-sj2)  (prep)  -> no sj load/add per element
//   - exp2(-si2) applied once per i after the shuffle reduce
//   epilogue per element: add, exp, fma  (was add,add,fma,exp,fma + mul)
// prep also writes out[i]=bias; main atomicAdds (R7-style, beat store+reduce).
//
// Frag map (16x16x32 bf16): lane l of tile t, half h: row=16*t+(l&15),
// k=32*h+(l>>4)*8..+7 -> chunk (t*2+h)*64+l.  A/B share lane->k map =>
// k-permutation cancels in A.B.  C/D: col=lane&15 (i), row=(lane>>4)*4+reg (j)
// [verified m89; R4-R10 passed]

#define NN 4096
#define DD 64
#define NPY 32                 // j-chunks; 8 j-tiles (256 j-rows) each
#define NT (NN / 16)           // 256 row-tiles

typedef __attribute__((ext_vector_type(8))) short bf16x8;
typedef __attribute__((ext_vector_type(8))) unsigned short u16x8;
typedef __attribute__((ext_vector_type(4))) float f32x4;

#define C2 0.028853901f        // log2(e)/50
#define SQK 0.2402244f         // sqrt(2*log2(e)/50)

static __device__ __forceinline__ unsigned short f2bf(float f) {
    unsigned int x = __float_as_uint(f);
    x += 0x7fffu + ((x >> 16) & 1u);          // RNE
    return (unsigned short)(x >> 16);
}

// ---------- prep: retile+convert (scaled), norms, ajp, out=bias ----------
__global__ __launch_bounds__(256) void svr_prep(const float* __restrict__ F,
                                                const float* __restrict__ alpha,
                                                const float* __restrict__ bias,
                                                u16x8* __restrict__ Ft,
                                                float* __restrict__ sq2,
                                                float* __restrict__ ajp,
                                                float* __restrict__ out) {
    __shared__ float part[256];
    const int tid = threadIdx.x;
    const int g = blockIdx.x * 256 + tid;           // 0..32767
    const int l = g & 63;
    const int h = (g >> 6) & 1;
    const int t = g >> 7;
    const int row = t * 16 + (l & 15);
    const int k0  = h * 32 + (l >> 4) * 8;

    const float4* src = reinterpret_cast<const float4*>(F + (size_t)row * DD + k0);
    const float4 v0 = src[0];
    const float4 v1 = src[1];
    u16x8 u;                                        // scaled by sqrt(K1)
    u[0] = f2bf(v0.x * SQK); u[1] = f2bf(v0.y * SQK);
    u[2] = f2bf(v0.z * SQK); u[3] = f2bf(v0.w * SQK);
    u[4] = f2bf(v1.x * SQK); u[5] = f2bf(v1.y * SQK);
    u[6] = f2bf(v1.z * SQK); u[7] = f2bf(v1.w * SQK);
    Ft[g] = u;

    float p = v0.x * v0.x;                          // unscaled norms
    p = fmaf(v0.y, v0.y, p); p = fmaf(v0.z, v0.z, p); p = fmaf(v0.w, v0.w, p);
    p = fmaf(v1.x, v1.x, p); p = fmaf(v1.y, v1.y, p); p = fmaf(v1.z, v1.z, p);
    p = fmaf(v1.w, v1.w, p);
    part[tid] = p;
    __syncthreads();
    if ((tid & 112) == 0) {    // one thread per row: tid in {0..15, 128..143}
        float s = part[tid]      + part[tid + 16] + part[tid + 32] + part[tid + 48]
                + part[tid + 64] + part[tid + 80] + part[tid + 96] + part[tid + 112];
        const float w = s * C2;                     // si2 = |f|^2 * log2(e)/50
        sq2[row] = w;
        ajp[row] = alpha[row] * exp2f(-w);          // alpha_j * exp2(-sj2)
    }
    if (g < NN) out[g] = bias[0];                   // re-init every call
}

// ---------- main: 4 i-tiles/wave, slim epilogue, atomicAdd ----------
__global__ __launch_bounds__(256) void svr_mfma4(const bf16x8* __restrict__ Ft,
                                                 const float* __restrict__ ajp,
                                                 const float* __restrict__ sq2,
                                                 float* __restrict__ out) {
    const int lane = threadIdx.x & 63;
    const int wave = threadIdx.x >> 6;
    const int ig   = blockIdx.x * 4 + wave;          // i-group 0..63 (64 rows)
    const int it0  = ig * 4;
    const int iBase = it0 * 16;
    const int p    = blockIdx.y;                     // 0..31
    const int jt0  = p * (NT / NPY);                 // 8 j-tiles
    const int kg   = lane >> 4;
    const int c    = lane & 15;

    // B-frags for 4 i-tiles (32 VGPR, resident) + i-side exp scales
    const bf16x8 b00 = Ft[(it0 + 0) * 128 + lane], b01 = Ft[(it0 + 0) * 128 + 64 + lane];
    const bf16x8 b10 = Ft[(it0 + 1) * 128 + lane], b11 = Ft[(it0 + 1) * 128 + 64 + lane];
    const bf16x8 b20 = Ft[(it0 + 2) * 128 + lane], b21 = Ft[(it0 + 2) * 128 + 64 + lane];
    const bf16x8 b30 = Ft[(it0 + 3) * 128 + lane], b31 = Ft[(it0 + 3) * 128 + 64 + lane];
    const float e0 = exp2f(-sq2[iBase + c]);
    const float e1 = exp2f(-sq2[iBase + 16 + c]);
    const float e2 = exp2f(-sq2[iBase + 32 + c]);
    const float e3 = exp2f(-sq2[iBase + 48 + c]);

    const float4* alv = reinterpret_cast<const float4*>(ajp);

    f32x4 acc0 = {0.f,0.f,0.f,0.f}, acc1 = {0.f,0.f,0.f,0.f};
    f32x4 acc2 = {0.f,0.f,0.f,0.f}, acc3 = {0.f,0.f,0.f,0.f};

    bf16x8 a0 = Ft[jt0 * 128 + lane];
    bf16x8 a1 = Ft[jt0 * 128 + 64 + lane];
    float4 aj = alv[jt0 * 4 + kg];

#pragma unroll
    for (int k = 0; k < NT / NPY; ++k) {
        bf16x8 n0, n1; float4 naj;
        if (k + 1 < NT / NPY) {                      // prefetch next j-tile
            const int jn = jt0 + k + 1;
            n0 = Ft[jn * 128 + lane];
            n1 = Ft[jn * 128 + 64 + lane];
            naj = alv[jn * 4 + kg];
        }
#define TILE(acc, bA, bB)                                                   \
        {                                                                   \
            f32x4 d0 = {0.f,0.f,0.f,0.f}, d1 = {0.f,0.f,0.f,0.f};           \
            d0 = __builtin_amdgcn_mfma_f32_16x16x32_bf16(a0, bA, d0, 0,0,0);\
            d1 = __builtin_amdgcn_mfma_f32_16x16x32_bf16(a1, bB, d1, 0,0,0);\
            acc.x = fmaf(exp2f(d0[0] + d1[0]), aj.x, acc.x);                \
            acc.y = fmaf(exp2f(d0[1] + d1[1]), aj.y, acc.y);                \
            acc.z = fmaf(exp2f(d0[2] + d1[2]), aj.z, acc.z);                \
            acc.w = fmaf(exp2f(d0[3] + d1[3]), aj.w, acc.w);                \
        }
        TILE(acc0, b00, b01)
        TILE(acc1, b10, b11)
        TILE(acc2, b20, b21)
        TILE(acc3, b30, b31)
#undef TILE
        a0 = n0; a1 = n1; aj = naj;
    }

    float s0 = (acc0.x + acc0.y) + (acc0.z + acc0.w);
    float s1 = (acc1.x + acc1.y) + (acc1.z + acc1.w);
    float s2 = (acc2.x + acc2.y) + (acc2.z + acc2.w);
    float s3 = (acc3.x + acc3.y) + (acc3.z + acc3.w);
    s0 += __shfl_xor(s0, 16); s0 += __shfl_xor(s0, 32);
    s1 += __shfl_xor(s1, 16); s1 += __shfl_xor(s1, 32);
    s2 += __shfl_xor(s2, 16); s2 += __shfl_xor(s2, 32);
    s3 += __shfl_xor(s3, 16); s3 += __shfl_xor(s3, 32);
    if (lane < 16) {                                 // apply exp2(-si2) once
        atomicAdd(&out[iBase      + lane], s0 * e0);
        atomicAdd(&out[iBase + 16 + lane], s1 * e1);
        atomicAdd(&out[iBase + 32 + lane], s2 * e2);
        atomicAdd(&out[iBase + 48 + lane], s3 * e3);
    }
}

// ---------------- launch ----------------
extern "C" void kernel_launch(void* const* d_in, const int* in_sizes, int n_in,
                              void* d_out, int out_size, void* d_ws, size_t ws_size,
                              hipStream_t stream) {
    const float* F     = (const float*)d_in[0];
    const float* alpha = (const float*)d_in[1];
    const float* bias  = (const float*)d_in[2];
    float* out = (float*)d_out;

    u16x8* Ft  = (u16x8*)d_ws;                                   // 512 KB scaled bf16
    float* sq2 = (float*)((char*)d_ws + (size_t)NN * DD * 2);    // 16 KB si2
    float* ajp = sq2 + NN;                                       // 16 KB alpha*exp2(-sj2)

    svr_prep<<<dim3(NN * DD / 8 / 256), dim3(256), 0, stream>>>(F, alpha, bias, Ft, sq2, ajp, out);
    svr_mfma4<<<dim3(16, NPY), dim3(256), 0, stream>>>((const bf16x8*)Ft, ajp, sq2, out);
}